// Round 7
// baseline (245.175 us; speedup 1.0000x reference)
//
#include <hip/hip_runtime.h>
#include <math.h>

#define DIMC 256
#define NHEADS 8
#define HDIM 32
#define CPBH 512
#define BB 2
#define NSEQ 2304
#define TAB 9025
#define TABP 9040                  // padded table stride
#define RTOT (BB*NHEADS*NSEQ)      // 36864
#define SPLITS 4
#define MSP (NSEQ/SPLITS)          // 576 m per split
#define NT (MSP/32)                // 18 m-tiles per split
#define PBS 34                     // pbuf row stride in u16
#define NCHUNK (NSEQ/32)           // 72
#define LOG2E 1.44269504088896340736f

#define IDXP_ELEMS    (NSEQ * NCHUNK * 16)             // 2,654,208
#define IDXP4_BLOCKS  (IDXP_ELEMS / 1024)              // 2592
#define CPB_BLOCKS    ((TAB + 63) / 64)                // 142
#define QKV_BLOCKS    (12 * 72)                        // 864

typedef unsigned short ushort;
typedef __attribute__((ext_vector_type(8))) short short8;
typedef __attribute__((ext_vector_type(4))) short short4v;
typedef __attribute__((ext_vector_type(4))) float f32x4;

#define MFMA16(a,b,c) __builtin_amdgcn_mfma_f32_16x16x32_bf16((a),(b),(c),0,0,0)

// async global->LDS 16B copy; dest = wave-uniform base + lane*16
#define GL16(SRC, DST) __builtin_amdgcn_global_load_lds( \
    (const __attribute__((address_space(1))) void*)(SRC), \
    (__attribute__((address_space(3))) void*)(DST), 16, 0, 0)

__device__ __forceinline__ ushort f2bf(float x) {          // RNE fp32->bf16
  unsigned u = __float_as_uint(x);
  u += 0x7FFFu + ((u >> 16) & 1u);
  return (ushort)(u >> 16);
}
__device__ __forceinline__ float bf2f(ushort b) {
  return __uint_as_float(((unsigned)b) << 16);
}
__device__ __forceinline__ float fexp2(float x) {
#if defined(__has_builtin)
#if __has_builtin(__builtin_amdgcn_exp2f)
  return __builtin_amdgcn_exp2f(x);
#else
  return exp2f(x);
#endif
#else
  return exp2f(x);
#endif
}
__device__ __forceinline__ unsigned pack_trunc(float p0, float p1) {
  return __builtin_amdgcn_perm(__float_as_uint(p1), __float_as_uint(p0), 0x07060302u);
}
// load 8 consecutive fp32, emit split-bf16 hi/lo frags
__device__ __forceinline__ void cvt8(const float* __restrict__ p, short8* hi, short8* lo) {
  float4 v0 = *(const float4*)p;
  float4 v1 = *(const float4*)(p + 4);
  float vv[8] = {v0.x, v0.y, v0.z, v0.w, v1.x, v1.y, v1.z, v1.w};
  short8 h, l;
#pragma unroll
  for (int i = 0; i < 8; ++i) {
    ushort hh = f2bf(vv[i]);
    h[i] = (short)hh;
    l[i] = (short)f2bf(vv[i] - bf2f(hh));
  }
  *hi = h; *lo = l;
}

// ======= idx pair-pack kernel (no LDS, pure memory) =======
__launch_bounds__(256)
__global__ void pack_kernel(const int* __restrict__ idx, unsigned* __restrict__ idxP) {
  int t4 = blockIdx.x * 256 + threadIdx.x;   // 0..663551
  int grp = t4 >> 4;                 // 0..41471
  int ch = grp % NCHUNK;
  int n4 = grp / NCHUNK;
  int m = ch * 32 + (t4 & 15);
  unsigned o[4];
#pragma unroll
  for (int i = 0; i < 4; ++i) {
    unsigned lo = (unsigned)idx[(size_t)(n4 * 4 + i) * NSEQ + m];
    unsigned hi = (unsigned)idx[(size_t)(n4 * 4 + i) * NSEQ + m + 16];
    o[i] = lo | (hi << 16);
  }
  *(uint4*)&idxP[(size_t)t4 * 4] = *(const uint4*)o;
}

// ======= PRE: cpb (blocks first) | fused QKV GEMM with in-block B-tile
// split-bf16 LDS staging (wq cvt done ONCE per block, not 16x) =======
__launch_bounds__(256)
__global__ void pre_kernel(const float* __restrict__ x, const float* __restrict__ wq,
                           const float* __restrict__ tbl, const float* __restrict__ W1,
                           const float* __restrict__ b1, const float* __restrict__ W2,
                           const float* __restrict__ b2,
                           const float* __restrict__ bias, const float* __restrict__ temp,
                           const float* __restrict__ sls, const float* __restrict__ qe,
                           ushort* __restrict__ qhi, ushort* __restrict__ qlo,
                           ushort* __restrict__ khi, ushort* __restrict__ klo,
                           ushort* __restrict__ vT, ushort* __restrict__ tabBf) {
  __shared__ __align__(16) ushort smemu[33792];   // 66 KB union
  int blk = blockIdx.x;
  int tid = threadIdx.x;

  if (blk < CPB_BLOCKS) {
    // ---- CPB MLP, LDS-tiled ----
    float* smem = (float*)smemu;
    float* w1b = smem;                  // 2048 f
    float* w2t = smem + 2048;           // 4096 f
    float* part = smem + 6144;          // 2048 f
    for (int i = tid; i < CPBH; i += 256) {
      w1b[i * 4 + 0] = W1[2 * i];
      w1b[i * 4 + 1] = W1[2 * i + 1];
      w1b[i * 4 + 2] = b1[i];
      w1b[i * 4 + 3] = 0.f;
    }
    for (int i = tid; i < CPBH * NHEADS; i += 256)
      w2t[(i & (CPBH - 1)) * NHEADS + (i >> 9)] = W2[i];
    int tl = tid & 63, jc = tid >> 6;
    int t = blk * 64 + tl;
    bool valid = t < TAB;
    float c0 = 0.f, c1 = 0.f;
    if (valid) { c0 = tbl[2 * t]; c1 = tbl[2 * t + 1]; }
    __syncthreads();
    float acc[NHEADS];
#pragma unroll
    for (int h = 0; h < NHEADS; ++h) acc[h] = 0.f;
    for (int j = jc * 128; j < jc * 128 + 128; ++j) {
      float4 wv = *(const float4*)&w1b[j * 4];
      float hid = fmaxf(fmaf(c0, wv.x, fmaf(c1, wv.y, wv.z)), 0.f);
      float4 wa = *(const float4*)&w2t[j * NHEADS];
      float4 wb = *(const float4*)&w2t[j * NHEADS + 4];
      acc[0] = fmaf(hid, wa.x, acc[0]);
      acc[1] = fmaf(hid, wa.y, acc[1]);
      acc[2] = fmaf(hid, wa.z, acc[2]);
      acc[3] = fmaf(hid, wa.w, acc[3]);
      acc[4] = fmaf(hid, wb.x, acc[4]);
      acc[5] = fmaf(hid, wb.y, acc[5]);
      acc[6] = fmaf(hid, wb.z, acc[6]);
      acc[7] = fmaf(hid, wb.w, acc[7]);
    }
#pragma unroll
    for (int h = 0; h < NHEADS; ++h) part[((size_t)jc * 64 + tl) * NHEADS + h] = acc[h];
    __syncthreads();
    if (jc == 0 && valid) {
#pragma unroll
      for (int h = 0; h < NHEADS; ++h) {
        float s = b2[h];
#pragma unroll
        for (int p = 0; p < 4; ++p) s += part[((size_t)p * 64 + tl) * NHEADS + h];
        tabBf[h * TABP + t] = f2bf(s * LOG2E);
      }
    }
  } else {
    // ---- fused QKV GEMM: B-tile (64 rows of wq) split-bf16 staged in LDS ----
    ushort* bsh = smemu;                 // [64][264] hi
    ushort* bsl = smemu + 64 * 264;      // [64][264] lo
    float (*vbuf)[65] = (float(*)[65])smemu;   // union, used after k-loop
    int t = blk - CPB_BLOCKS;
    int n0 = (t % 12) * 64, m0 = (t / 12) * 64;
    int lane = tid & 63, w = tid >> 6;
    int g = lane >> 4, c = lane & 15;
    int mw = m0 + w * 16;
    const int K = DIMC;

    {   // stage: each thread converts 64 elems (8 cvt8), once per block
      int rr = tid >> 2, cq = (tid & 3) * 64;
#pragma unroll
      for (int j = 0; j < 64; j += 8) {
        short8 hh, ll;
        cvt8(&wq[(size_t)(n0 + rr) * K + cq + j], &hh, &ll);
        *(short8*)&bsh[rr * 264 + cq + j] = hh;
        *(short8*)&bsl[rr * 264 + cq + j] = ll;
      }
    }
    __syncthreads();

    f32x4 acc[4] = {{0,0,0,0},{0,0,0,0},{0,0,0,0},{0,0,0,0}};
#pragma unroll 2
    for (int k0 = 0; k0 < K; k0 += 32) {
      short8 ah, al;
      cvt8(&x[(size_t)(mw + c) * K + k0 + g * 8], &ah, &al);
#pragma unroll
      for (int nt = 0; nt < 4; ++nt) {
        int br = (nt * 16 + c) * 264 + k0 + g * 8;
        short8 bh = *(const short8*)&bsh[br];
        short8 bl = *(const short8*)&bsl[br];
        acc[nt] = MFMA16(ah, bh, acc[nt]);
        acc[nt] = MFMA16(al, bh, acc[nt]);
        acc[nt] = MFMA16(ah, bl, acc[nt]);
      }
    }
#pragma unroll
    for (int nt = 0; nt < 4; ++nt) {
      float bv = bias[n0 + nt * 16 + c];
#pragma unroll
      for (int r = 0; r < 4; ++r) acc[nt][r] += bv;
    }
    __syncthreads();   // all waves done reading bsh/bsl before vbuf overwrites

    int b = (m0 >= NSEQ) ? 1 : 0;
    int nb = m0 - b * NSEQ;
    int sect = n0 >> 8;
    int hloc = (n0 & 255) >> 5;

    if (sect < 2) {
#pragma unroll
      for (int H = 0; H < 2; ++H) {
        int head = hloc + H;
        float scale = (sect == 0) ? log1pf(expf(temp[head])) * sls[0] * LOG2E : 0.f;
#pragma unroll
        for (int r = 0; r < 4; ++r) {
          float ss = acc[2*H][r]*acc[2*H][r] + acc[2*H+1][r]*acc[2*H+1][r];
          ss += __shfl_xor(ss, 1);
          ss += __shfl_xor(ss, 2);
          ss += __shfl_xor(ss, 4);
          ss += __shfl_xor(ss, 8);
          float inv = 1.f / fmaxf(sqrtf(ss), 1e-12f);
#pragma unroll
          for (int half = 0; half < 2; ++half) {
            int d = half * 16 + c;
            float val = acc[2*H + half][r] * inv;
            if (sect == 0) val = (val + qe[head * HDIM + d]) * scale;
            vbuf[w * 16 + g * 4 + r][H * 32 + d] = val;
          }
        }
      }
      __syncthreads();
      int plane = tid >> 7;
      int seg = tid & 127;
      int head = seg >> 6, row = seg & 63;
      const float* srcrow = &vbuf[row][head * 32];
      ushort out16[32];
#pragma unroll
      for (int i = 0; i < 32; ++i) {
        float v = srcrow[i];
        ushort hh = f2bf(v);
        out16[i] = plane ? f2bf(v - bf2f(hh)) : hh;
      }
      ushort* dstp = plane ? (sect == 0 ? qlo : klo) : (sect == 0 ? qhi : khi);
      size_t off = ((size_t)(b * NHEADS + hloc + head) * NSEQ + nb + row) * HDIM;
#pragma unroll
      for (int q4 = 0; q4 < 4; ++q4)
        *(int4*)&dstp[off + q4 * 8] = ((int4*)out16)[q4];
    } else {
#pragma unroll
      for (int nt = 0; nt < 4; ++nt)
#pragma unroll
        for (int r = 0; r < 4; ++r)
          vbuf[w * 16 + g * 4 + r][nt * 16 + c] = acc[nt][r];
      __syncthreads();
      int hbase = (n0 - 512) >> 5;
#pragma unroll
      for (int it = 0; it < 16; ++it) {
        int dloc = (tid >> 6) * 16 + it;
        int p = tid & 63;
        int pp = p & 31;
        int nsrc = (p & 32) + (pp & 1) * 16 + (pp >> 1);
        float v = vbuf[nsrc][dloc];
        int head = hbase + (dloc >> 5), d = dloc & 31;
        vT[((size_t)((b * NHEADS + head) * HDIM + d)) * NSEQ + nb + p] = f2bf(v);
      }
    }
  }
}

// ------- MFMA flash attention: 4-deep async-LDS staging ring with COUNTED
// vmcnt + raw s_barrier (T3/T4). Per iter: wait vmcnt(8) (own 3 DMAs of the
// tile consumed this iter, issued 3 iters ago) -> barrier (cross-wave union,
// also proves dest buffer free) -> issue next idxP + STAGE -> compute.
// 2 newer tiles stay in flight ACROSS barriers; the __syncthreads vmcnt(0)
// drain (r5/r6's ~2900 cyc/iter stall) is gone. Wrap-padded issue keeps the
// vmcnt count constant (dummy re-stages hit L2). 2 blocks/CU (76.3KB LDS).
__launch_bounds__(256)
__global__ void attn_kernel(const ushort* __restrict__ qhi, const ushort* __restrict__ qlo,
                            const ushort* __restrict__ khi, const ushort* __restrict__ klo,
                            const ushort* __restrict__ vT, const ushort* __restrict__ tabBf,
                            const unsigned* __restrict__ idxP,
                            float* __restrict__ pO, float* __restrict__ pL) {
  __shared__ ushort tbf[9216];                         // 18 KB (TAB=9025 fits)
  __shared__ __align__(16) ushort pbuf[8][16 * PBS];   // 8.5 KB
  __shared__ __align__(16) ushort stg[4][6144];        // 4 x 12 KB K/V ring
  int tid = threadIdx.x;
  int lane = tid & 63;
  int w = tid >> 6;

  int bid = blockIdx.x;                 // 0..1151
  int qb = bid >> 5;                    // 0..35 : 64-q-row tile
  int k8 = bid & 7;
  int j4 = (bid >> 3) & 3;
  int y  = k8 + 8 * j4;                 // 0..31 ; fixed y -> fixed bid%8 -> one XCD
  int s = y & 3, h = y >> 2;

  const ushort* tsrc = tabBf + h * TABP;
#pragma unroll
  for (int i = 0; i < 4; ++i) {
    int off = i * 2048 + tid * 8;
    *(int4*)&tbf[off] = *(const int4*)&tsrc[off];
  }
  if (tid < 128) {
    int off = 8192 + tid * 8;
    *(int4*)&tbf[off] = *(const int4*)&tsrc[off];
  }

  int g = lane >> 4, c = lane & 15;
  int q0 = qb * 64 + w * 16;
  int qg0 = q0 >> 2;
  size_t rowA = (size_t)h * NSEQ;              // batch 0, head h
  size_t rowB = (size_t)(NHEADS + h) * NSEQ;   // batch 1, head h
  int m0 = s * MSP;

  // ---- staging geometry: thread covers 16B unit u=tid&127 of 3 subtile-pairs
  int su   = tid & 127;
  int srow = su & 31;          // tile row (K: m-row ; V: dim)
  int sslt = su >> 5;          // 16B slot
  const ushort* kb0 = (tid < 128) ? khi : klo;
  const ushort* sA0 = kb0 + (rowA + m0 + srow) * HDIM + sslt * 8;
  const ushort* sB0 = kb0 + (rowB + m0 + srow) * HDIM + sslt * 8;
  const ushort* sV0 = vT + ((size_t)(((tid < 128) ? h : NHEADS + h) * HDIM + srow)) * NSEQ
                      + m0 + sslt * 8;
  unsigned dwb = (unsigned)(tid & 192) * 8;    // wave-uniform dest base (elems)

  // STAGE(dst ring buffer index, source tile index 0..NT-1): 3 async DMAs.
#define STAGE(BUF, TILE) do {                              \
    ushort* d_ = &stg[(BUF)][0] + dwb;                     \
    GL16(sA0 + (size_t)(TILE) * 32 * HDIM, d_);            \
    GL16(sB0 + (size_t)(TILE) * 32 * HDIM, d_ + 2048);     \
    GL16(sV0 + (TILE) * 32,                d_ + 4096);     \
  } while (0)

  short8 qAh = *(const short8*)&qhi[(rowA + q0 + c) * HDIM + g * 8];
  short8 qAl = *(const short8*)&qlo[(rowA + q0 + c) * HDIM + g * 8];
  short8 qBh = *(const short8*)&qhi[(rowB + q0 + c) * HDIM + g * 8];
  short8 qBl = *(const short8*)&qlo[(rowB + q0 + c) * HDIM + g * 8];

  unsigned oIb = (unsigned)(((unsigned)(qg0 + g) * NCHUNK + (m0 >> 5)) * 64 + c * 4);
  uint4 ia0 = *(const uint4*)&idxP[oIb];            // idx tile 0
  uint4 ia1 = *(const uint4*)&idxP[oIb + 64];       // idx tile 1

  STAGE(0, 0);
  STAGE(1, 1);
  STAGE(2, 2);
  __syncthreads();               // prologue: full drain (tbf + 3 stages)

  short one = (c == 0) ? (short)0x3F80 : (short)0;
  short8 onesB = {one, one, one, one, one, one, one, one};

  f32x4 oa0 = {0,0,0,0}, oa1 = {0,0,0,0}, ob0 = {0,0,0,0}, ob1 = {0,0,0,0};
  f32x4 la = {0,0,0,0}, lb = {0,0,0,0};
  ushort* pba = pbuf[w * 2];
  ushort* pbb = pbuf[w * 2 + 1];

  int kbo = g * 256 + c * 8;      // frag base within a 2KB subtile (elems)

  for (int t = 0; t < NT; ++t) {
    // A: tile t's own DMAs done (allowed outstanding: idx(t),S(t+1)x3,
    //    idx(t+1),S(t+2)x3 = 8); barrier -> tile t visible to all waves AND
    //    ring buffer (t+3)&3 (last read at iter t-1) is free for re-issue.
    asm volatile("s_waitcnt vmcnt(8)" ::: "memory");
    __builtin_amdgcn_s_barrier();
    __builtin_amdgcn_sched_barrier(0);

    // B: constant 4 VMEM per iter (wrap-padded at the tail; dummy stages
    //    land in a free buffer and are never read).
    int t2 = t + 2; if (t2 >= NT) t2 -= NT;
    int t3 = t + 3; if (t3 >= NT) t3 -= NT;
    uint4 ian = *(const uint4*)&idxP[oIb + (unsigned)t2 * 64];
    STAGE((t + 3) & 3, t3);

    // C: compute on stg[t&3] with idx tile t (= ia0)
    const ushort* S = &stg[t & 3][0];
    short8 ak0h = *(const short8*)&S[kbo];
    short8 ak1h = *(const short8*)&S[kbo + 128];
    short8 ak0l = *(const short8*)&S[1024 + kbo];
    short8 ak1l = *(const short8*)&S[1024 + kbo + 128];
    short8 bk0h = *(const short8*)&S[2048 + kbo];
    short8 bk1h = *(const short8*)&S[2048 + kbo + 128];
    short8 bk0l = *(const short8*)&S[3072 + kbo];
    short8 bk1l = *(const short8*)&S[3072 + kbo + 128];

    f32x4 sa0 = {0,0,0,0}, sa1 = {0,0,0,0}, sb0 = {0,0,0,0}, sb1 = {0,0,0,0};
    sa0 = MFMA16(qAh, ak0h, sa0);
    sa1 = MFMA16(qAh, ak1h, sa1);
    sb0 = MFMA16(qBh, bk0h, sb0);
    sb1 = MFMA16(qBh, bk1h, sb1);
    sa0 = MFMA16(qAl, ak0h, sa0);
    sa1 = MFMA16(qAl, ak1h, sa1);
    sb0 = MFMA16(qBl, bk0h, sb0);
    sb1 = MFMA16(qBl, bk1h, sb1);
    sa0 = MFMA16(qAh, ak0l, sa0);
    sa1 = MFMA16(qAh, ak1l, sa1);
    sb0 = MFMA16(qBh, bk0l, sb0);
    sb1 = MFMA16(qBh, bk1l, sb1);

    // bias gathers (batch-shared) + exp2 + pack
    unsigned ip[4] = {ia0.x, ia0.y, ia0.z, ia0.w};
    float b0[4], b1[4];
#pragma unroll
    for (int r = 0; r < 4; ++r) {
      b0[r] = bf2f(tbf[ip[r] & 0xFFFF]);
      b1[r] = bf2f(tbf[ip[r] >> 16]);
    }
#pragma unroll
    for (int r = 0; r < 4; ++r) {
      float pA0 = fexp2(sa0[r] + b0[r]);
      float pA1 = fexp2(sa1[r] + b1[r]);
      *(unsigned*)&pba[(g * 4 + r) * PBS + 2 * c] = pack_trunc(pA0, pA1);
      float pB0 = fexp2(sb0[r] + b0[r]);
      float pB1 = fexp2(sb1[r] + b1[r]);
      *(unsigned*)&pbb[(g * 4 + r) * PBS + 2 * c] = pack_trunc(pB0, pB1);
    }

    short4v paA = *(const short4v*)&pba[c * PBS + g * 8];
    short4v paB = *(const short4v*)&pba[c * PBS + g * 8 + 4];
    short8 pfa = __builtin_shufflevector(paA, paB, 0, 1, 2, 3, 4, 5, 6, 7);
    short4v pbA = *(const short4v*)&pbb[c * PBS + g * 8];
    short4v pbB = *(const short4v*)&pbb[c * PBS + g * 8 + 4];
    short8 pfb = __builtin_shufflevector(pbA, pbB, 0, 1, 2, 3, 4, 5, 6, 7);

    short8 vf0 = *(const short8*)&S[4096 + kbo];
    short8 vf1 = *(const short8*)&S[4096 + kbo + 128];
    short8 wf0 = *(const short8*)&S[5120 + kbo];
    short8 wf1 = *(const short8*)&S[5120 + kbo + 128];

    oa0 = MFMA16(pfa, vf0, oa0);
    oa1 = MFMA16(pfa, vf1, oa1);
    ob0 = MFMA16(pfb, wf0, ob0);
    ob1 = MFMA16(pfb, wf1, ob1);
    la  = MFMA16(pfa, onesB, la);
    lb  = MFMA16(pfb, onesB, lb);

    ia0 = ia1; ia1 = ian;      // rotate idx pipeline (static, no dyn index)
  }
#undef STAGE

  // all DMAs (incl. wrap-padded dummies) must land before block retires
  asm volatile("s_waitcnt vmcnt(0)" ::: "memory");

  size_t prowA = (size_t)s * RTOT + rowA;
  size_t prowB = (size_t)s * RTOT + rowB;
#pragma unroll
  for (int r = 0; r < 4; ++r) {
    size_t pra = prowA + q0 + g * 4 + r;
    pO[pra * HDIM + c]      = oa0[r];
    pO[pra * HDIM + 16 + c] = oa1[r];
    size_t prb = prowB + q0 + g * 4 + r;
    pO[prb * HDIM + c]      = ob0[r];
    pO[prb * HDIM + 16 + c] = ob1[r];
    if (c == 0) { pL[pra] = la[r]; pL[prb] = lb[r]; }
  }
}

// ------- fused merge + proj GEMM: 32-row tiles, 144 blocks -------
#define ALD 264
__launch_bounds__(256)
__global__ void gemm_proj_fused(const float* __restrict__ pO, const float* __restrict__ pL,
                                const float* __restrict__ Wp,
                                const float* __restrict__ bias, float* __restrict__ C) {
  __shared__ __align__(16) ushort Ahs[32 * ALD];
  __shared__ __align__(16) ushort Als[32 * ALD];
  int tid = threadIdx.x;
  int m0 = blockIdx.x * 32;
  int b = (m0 >= NSEQ) ? 1 : 0;
  int nb = m0 - b * NSEQ;

  {
    int rr = tid >> 3;          // 0..31 row
    int q  = tid & 3;           // 8-float chunk within head
    int hp = (tid >> 2) & 1;    // head half: heads hp*4 .. hp*4+3
    int n = nb + rr;
#pragma unroll
    for (int hh = 0; hh < 4; ++hh) {
      int h = hp * 4 + hh;
      size_t bhn = (size_t)(b * NHEADS + h) * NSEQ + n;
      float L = 0.f;
#pragma unroll
      for (int sp = 0; sp < SPLITS; ++sp) L += pL[(size_t)sp * RTOT + bhn];
      float inv = 1.f / L;
      float a[8] = {0.f, 0.f, 0.f, 0.f, 0.f, 0.f, 0.f, 0.f};
#pragma unroll
      for (int sp = 0; sp < SPLITS; ++sp) {
        const float* src = &pO[((size_t)sp * RTOT + bhn) * HDIM + q * 8];
        float4 v0 = *(const float4*)&src[0];
        float4 v1 = *(const float4*)&src[4];
        a[0] += v0.x; a[1] += v0.y; a[2] += v0.z; a[3] += v0.w;
        a[4] += v1.x; a[5] += v1.y; a[6] += v1.z; a[7] += v1.w;
      }
      ushort hi8[8], lo8[8];
#pragma unroll
      for (int i = 0; i < 8; ++i) {
        float v = a[i] * inv;
        ushort hh2 = f2bf(v);
        hi8[i] = hh2;
        lo8[i] = f2bf(v - bf2f(hh2));
      }
      int k = h * 32 + q * 8;
      *(int4*)&Ahs[rr * ALD + k] = *(int4*)hi8;
      *(int4*)&Als[rr * ALD + k] = *(int4*)lo8;
    }
  }
  __syncthreads();

  int lane = tid & 63, w = tid >> 6;
  int g = lane >> 4, c = lane & 15;
  int n0 = w * 64;
  f32x4 acc[2][4] = {};
  for (int k0 = 0; k0 < DIMC; k0 += 32) {
    short8 bfh[4], bfl[4];
#pragma unroll
    for (int nt = 0; nt < 4; ++nt)
      cvt8(&Wp[(size_t)(n0 + nt * 16 + c) * DIMC + k0 + g * 8], &bfh[nt], &bfl[nt]);
#pragma unroll
    for (int mt = 0; mt < 2; ++mt) {
      short8 ah = *(const short8*)&Ahs[(mt * 16 + c) * ALD + k0 + g * 8];
      short8 al = *(const short8*)&Als[(mt * 16 + c) * ALD + k0 + g * 8];
#pragma unroll
      for (int nt = 0; nt < 4; ++nt) {
        acc[mt][nt] = MFMA16(ah, bfh[nt], acc[mt][nt]);
        acc[mt][nt] = MFMA16(al, bfh[nt], acc[mt][nt]);
        acc[mt][nt] = MFMA16(ah, bfl[nt], acc[mt][nt]);
      }
    }
  }
#pragma unroll
  for (int nt = 0; nt < 4; ++nt) {
    float bv = bias[n0 + nt * 16 + c];
#pragma unroll
    for (int mt = 0; mt < 2; ++mt)
#pragma unroll
      for (int r = 0; r < 4; ++r)
        C[(size_t)(m0 + mt * 16 + g * 4 + r) * DIMC + n0 + nt * 16 + c] = acc[mt][nt][r] + bv;
  }
}

extern "C" void kernel_launch(void* const* d_in, const int* in_sizes, int n_in,
                              void* d_out, int out_size, void* d_ws, size_t ws_size,
                              hipStream_t stream) {
  const float* x    = (const float*)d_in[0];
  const int*   idx  = (const int*)d_in[1];
  const float* tbl  = (const float*)d_in[2];
  const float* sls  = (const float*)d_in[3];
  const float* Wqkv = (const float*)d_in[5];
  const float* bqkv = (const float*)d_in[6];
  const float* temp = (const float*)d_in[7];
  const float* qe   = (const float*)d_in[8];
  const float* Wp   = (const float*)d_in[9];
  const float* bp   = (const float*)d_in[10];
  const float* W1   = (const float*)d_in[11];
  const float* b1   = (const float*)d_in[12];
  const float* W2   = (const float*)d_in[13];
  const float* b2   = (const float*)d_in[14];

  float* ws   = (float*)d_ws;
  float* pO   = ws;                                       // 4*RTOT*HDIM = 4,718,592 f
  float* pL   = pO + (size_t)SPLITS * RTOT * HDIM;        // 147,456 f
  unsigned* idxP = (unsigned*)(pL + (size_t)SPLITS * RTOT);
  ushort* u   = (ushort*)(idxP + IDXP_ELEMS);
  ushort* qhi = u;                u += (size_t)RTOT * HDIM;
  ushort* qlo = u;                u += (size_t)RTOT * HDIM;
  ushort* khi = u;                u += (size_t)RTOT * HDIM;
  ushort* klo = u;                u += (size_t)RTOT * HDIM;
  ushort* vT  = u;                u += (size_t)RTOT * HDIM;
  ushort* tabBf = u;              u += 73728;
  float* out  = (float*)d_out;

  pack_kernel<<<dim3(IDXP4_BLOCKS), dim3(256), 0, stream>>>(idx, idxP);
  pre_kernel<<<dim3(CPB_BLOCKS + QKV_BLOCKS), dim3(256), 0, stream>>>(
      x, Wqkv, tbl, W1, b1, W2, b2, bqkv, temp, sls, qe,
      qhi, qlo, khi, klo, vT, tabBf);
  attn_kernel<<<dim3((NSEQ / 64) * NHEADS * SPLITS), dim3(256), 0, stream>>>(
      qhi, qlo, khi, klo, vT, tabBf, idxP, pO, pL);
  gemm_proj_fused<<<dim3((BB * NSEQ) / 32), dim3(256), 0, stream>>>(
      pO, pL, Wp, bp, out);
}

// Round 8
// 202.585 us; speedup vs baseline: 1.2102x; 1.2102x over previous
//
#include <hip/hip_runtime.h>
#include <math.h>

#define DIMC 256
#define NHEADS 8
#define HDIM 32
#define CPBH 512
#define BB 2
#define NSEQ 2304
#define TAB 9025
#define TABP 9040                  // padded table stride
#define RTOT (BB*NHEADS*NSEQ)      // 36864
#define SPLITS 4
#define MSP (NSEQ/SPLITS)          // 576 m per split
#define PBS 36                     // pbuf row stride in u16 (r5 value)
#define NCHUNK (NSEQ/32)           // 72
#define LOG2E 1.44269504088896340736f

#define IDXP_ELEMS    (NSEQ * NCHUNK * 16)             // 2,654,208
#define IDXP4_BLOCKS  (IDXP_ELEMS / 1024)              // 2592
#define CPB_BLOCKS    ((TAB + 63) / 64)                // 142
#define QKV_BLOCKS    (12 * 72)                        // 864

typedef unsigned short ushort;
typedef __attribute__((ext_vector_type(8))) short short8;
typedef __attribute__((ext_vector_type(4))) short short4v;
typedef __attribute__((ext_vector_type(4))) float f32x4;
typedef __attribute__((ext_vector_type(4))) unsigned uint4v;

#define MFMA16(a,b,c) __builtin_amdgcn_mfma_f32_16x16x32_bf16((a),(b),(c),0,0,0)

// async global->LDS 16B copy; dest = wave-uniform base + lane*16
#define GL16(SRC, DST) __builtin_amdgcn_global_load_lds( \
    (const __attribute__((address_space(1))) void*)(SRC), \
    (__attribute__((address_space(3))) void*)(DST), 16, 0, 0)

__device__ __forceinline__ ushort f2bf(float x) {          // RNE fp32->bf16
  unsigned u = __float_as_uint(x);
  u += 0x7FFFu + ((u >> 16) & 1u);
  return (ushort)(u >> 16);
}
__device__ __forceinline__ float bf2f(ushort b) {
  return __uint_as_float(((unsigned)b) << 16);
}
__device__ __forceinline__ float fexp2(float x) {
#if defined(__has_builtin)
#if __has_builtin(__builtin_amdgcn_exp2f)
  return __builtin_amdgcn_exp2f(x);
#else
  return exp2f(x);
#endif
#else
  return exp2f(x);
#endif
}
__device__ __forceinline__ unsigned pack_trunc(float p0, float p1) {
  return __builtin_amdgcn_perm(__float_as_uint(p1), __float_as_uint(p0), 0x07060302u);
}
// load 8 consecutive fp32, emit split-bf16 hi/lo frags
__device__ __forceinline__ void cvt8(const float* __restrict__ p, short8* hi, short8* lo) {
  float4 v0 = *(const float4*)p;
  float4 v1 = *(const float4*)(p + 4);
  float vv[8] = {v0.x, v0.y, v0.z, v0.w, v1.x, v1.y, v1.z, v1.w};
  short8 h, l;
#pragma unroll
  for (int i = 0; i < 8; ++i) {
    ushort hh = f2bf(vv[i]);
    h[i] = (short)hh;
    l[i] = (short)f2bf(vv[i] - bf2f(hh));
  }
  *hi = h; *lo = l;
}

// ======= idx pair-pack kernel (no LDS, pure memory) =======
__launch_bounds__(256)
__global__ void pack_kernel(const int* __restrict__ idx, unsigned* __restrict__ idxP) {
  int t4 = blockIdx.x * 256 + threadIdx.x;   // 0..663551
  int grp = t4 >> 4;                 // 0..41471
  int ch = grp % NCHUNK;
  int n4 = grp / NCHUNK;
  int m = ch * 32 + (t4 & 15);
  unsigned o[4];
#pragma unroll
  for (int i = 0; i < 4; ++i) {
    unsigned lo = (unsigned)idx[(size_t)(n4 * 4 + i) * NSEQ + m];
    unsigned hi = (unsigned)idx[(size_t)(n4 * 4 + i) * NSEQ + m + 16];
    o[i] = lo | (hi << 16);
  }
  *(uint4*)&idxP[(size_t)t4 * 4] = *(const uint4*)o;
}

// ======= PRE: cpb (blocks first) | fused QKV GEMM with in-block B-tile
// split-bf16 LDS staging (wq cvt done ONCE per block, not 16x) =======
__launch_bounds__(256)
__global__ void pre_kernel(const float* __restrict__ x, const float* __restrict__ wq,
                           const float* __restrict__ tbl, const float* __restrict__ W1,
                           const float* __restrict__ b1, const float* __restrict__ W2,
                           const float* __restrict__ b2,
                           const float* __restrict__ bias, const float* __restrict__ temp,
                           const float* __restrict__ sls, const float* __restrict__ qe,
                           ushort* __restrict__ qhi, ushort* __restrict__ qlo,
                           ushort* __restrict__ khi, ushort* __restrict__ klo,
                           ushort* __restrict__ vT, ushort* __restrict__ tabBf) {
  __shared__ __align__(16) ushort smemu[33792];   // 66 KB union
  int blk = blockIdx.x;
  int tid = threadIdx.x;

  if (blk < CPB_BLOCKS) {
    // ---- CPB MLP, LDS-tiled ----
    float* smem = (float*)smemu;
    float* w1b = smem;                  // 2048 f
    float* w2t = smem + 2048;           // 4096 f
    float* part = smem + 6144;          // 2048 f
    for (int i = tid; i < CPBH; i += 256) {
      w1b[i * 4 + 0] = W1[2 * i];
      w1b[i * 4 + 1] = W1[2 * i + 1];
      w1b[i * 4 + 2] = b1[i];
      w1b[i * 4 + 3] = 0.f;
    }
    for (int i = tid; i < CPBH * NHEADS; i += 256)
      w2t[(i & (CPBH - 1)) * NHEADS + (i >> 9)] = W2[i];
    int tl = tid & 63, jc = tid >> 6;
    int t = blk * 64 + tl;
    bool valid = t < TAB;
    float c0 = 0.f, c1 = 0.f;
    if (valid) { c0 = tbl[2 * t]; c1 = tbl[2 * t + 1]; }
    __syncthreads();
    float acc[NHEADS];
#pragma unroll
    for (int h = 0; h < NHEADS; ++h) acc[h] = 0.f;
    for (int j = jc * 128; j < jc * 128 + 128; ++j) {
      float4 wv = *(const float4*)&w1b[j * 4];
      float hid = fmaxf(fmaf(c0, wv.x, fmaf(c1, wv.y, wv.z)), 0.f);
      float4 wa = *(const float4*)&w2t[j * NHEADS];
      float4 wb = *(const float4*)&w2t[j * NHEADS + 4];
      acc[0] = fmaf(hid, wa.x, acc[0]);
      acc[1] = fmaf(hid, wa.y, acc[1]);
      acc[2] = fmaf(hid, wa.z, acc[2]);
      acc[3] = fmaf(hid, wa.w, acc[3]);
      acc[4] = fmaf(hid, wb.x, acc[4]);
      acc[5] = fmaf(hid, wb.y, acc[5]);
      acc[6] = fmaf(hid, wb.z, acc[6]);
      acc[7] = fmaf(hid, wb.w, acc[7]);
    }
#pragma unroll
    for (int h = 0; h < NHEADS; ++h) part[((size_t)jc * 64 + tl) * NHEADS + h] = acc[h];
    __syncthreads();
    if (jc == 0 && valid) {
#pragma unroll
      for (int h = 0; h < NHEADS; ++h) {
        float s = b2[h];
#pragma unroll
        for (int p = 0; p < 4; ++p) s += part[((size_t)p * 64 + tl) * NHEADS + h];
        tabBf[h * TABP + t] = f2bf(s * LOG2E);
      }
    }
  } else {
    // ---- fused QKV GEMM: B-tile (64 rows of wq) split-bf16 staged in LDS ----
    ushort* bsh = smemu;                 // [64][264] hi
    ushort* bsl = smemu + 64 * 264;      // [64][264] lo
    float (*vbuf)[65] = (float(*)[65])smemu;   // union, used after k-loop
    int t = blk - CPB_BLOCKS;
    int n0 = (t % 12) * 64, m0 = (t / 12) * 64;
    int lane = tid & 63, w = tid >> 6;
    int g = lane >> 4, c = lane & 15;
    int mw = m0 + w * 16;
    const int K = DIMC;

    {   // stage: each thread converts 64 elems (8 cvt8), once per block
      int rr = tid >> 2, cq = (tid & 3) * 64;
#pragma unroll
      for (int j = 0; j < 64; j += 8) {
        short8 hh, ll;
        cvt8(&wq[(size_t)(n0 + rr) * K + cq + j], &hh, &ll);
        *(short8*)&bsh[rr * 264 + cq + j] = hh;
        *(short8*)&bsl[rr * 264 + cq + j] = ll;
      }
    }
    __syncthreads();

    f32x4 acc[4] = {{0,0,0,0},{0,0,0,0},{0,0,0,0},{0,0,0,0}};
#pragma unroll 2
    for (int k0 = 0; k0 < K; k0 += 32) {
      short8 ah, al;
      cvt8(&x[(size_t)(mw + c) * K + k0 + g * 8], &ah, &al);
#pragma unroll
      for (int nt = 0; nt < 4; ++nt) {
        int br = (nt * 16 + c) * 264 + k0 + g * 8;
        short8 bh = *(const short8*)&bsh[br];
        short8 bl = *(const short8*)&bsl[br];
        acc[nt] = MFMA16(ah, bh, acc[nt]);
        acc[nt] = MFMA16(al, bh, acc[nt]);
        acc[nt] = MFMA16(ah, bl, acc[nt]);
      }
    }
#pragma unroll
    for (int nt = 0; nt < 4; ++nt) {
      float bv = bias[n0 + nt * 16 + c];
#pragma unroll
      for (int r = 0; r < 4; ++r) acc[nt][r] += bv;
    }
    __syncthreads();   // all waves done reading bsh/bsl before vbuf overwrites

    int b = (m0 >= NSEQ) ? 1 : 0;
    int nb = m0 - b * NSEQ;
    int sect = n0 >> 8;
    int hloc = (n0 & 255) >> 5;

    if (sect < 2) {
#pragma unroll
      for (int H = 0; H < 2; ++H) {
        int head = hloc + H;
        float scale = (sect == 0) ? log1pf(expf(temp[head])) * sls[0] * LOG2E : 0.f;
#pragma unroll
        for (int r = 0; r < 4; ++r) {
          float ss = acc[2*H][r]*acc[2*H][r] + acc[2*H+1][r]*acc[2*H+1][r];
          ss += __shfl_xor(ss, 1);
          ss += __shfl_xor(ss, 2);
          ss += __shfl_xor(ss, 4);
          ss += __shfl_xor(ss, 8);
          float inv = 1.f / fmaxf(sqrtf(ss), 1e-12f);
#pragma unroll
          for (int half = 0; half < 2; ++half) {
            int d = half * 16 + c;
            float val = acc[2*H + half][r] * inv;
            if (sect == 0) val = (val + qe[head * HDIM + d]) * scale;
            vbuf[w * 16 + g * 4 + r][H * 32 + d] = val;
          }
        }
      }
      __syncthreads();
      int plane = tid >> 7;
      int seg = tid & 127;
      int head = seg >> 6, row = seg & 63;
      const float* srcrow = &vbuf[row][head * 32];
      ushort out16[32];
#pragma unroll
      for (int i = 0; i < 32; ++i) {
        float v = srcrow[i];
        ushort hh = f2bf(v);
        out16[i] = plane ? f2bf(v - bf2f(hh)) : hh;
      }
      ushort* dstp = plane ? (sect == 0 ? qlo : klo) : (sect == 0 ? qhi : khi);
      size_t off = ((size_t)(b * NHEADS + hloc + head) * NSEQ + nb + row) * HDIM;
#pragma unroll
      for (int q4 = 0; q4 < 4; ++q4)
        *(int4*)&dstp[off + q4 * 8] = ((int4*)out16)[q4];
    } else {
#pragma unroll
      for (int nt = 0; nt < 4; ++nt)
#pragma unroll
        for (int r = 0; r < 4; ++r)
          vbuf[w * 16 + g * 4 + r][nt * 16 + c] = acc[nt][r];
      __syncthreads();
      int hbase = (n0 - 512) >> 5;
#pragma unroll
      for (int it = 0; it < 16; ++it) {
        int dloc = (tid >> 6) * 16 + it;
        int p = tid & 63;
        int pp = p & 31;
        int nsrc = (p & 32) + (pp & 1) * 16 + (pp >> 1);
        float v = vbuf[nsrc][dloc];
        int head = hbase + (dloc >> 5), d = dloc & 31;
        vT[((size_t)((b * NHEADS + head) * HDIM + d)) * NSEQ + nb + p] = f2bf(v);
      }
    }
  }
}

// ------- MFMA flash attention: r5's proven 2-phase async-LDS dbuf structure
// (57.7us), restored verbatim. Only change: NON-TEMPORAL hints on the
// zero-reuse streams (idxP loads 10.6MB; pO/pL epilogue stores 19MB) so they
// don't evict the shared K/V slices from the per-XCD L2 (r6 diagnosed L2
// pollution as the residency-scaling poison). No schedule/occupancy change.
__launch_bounds__(256)
__global__ void attn_kernel(const ushort* __restrict__ qhi, const ushort* __restrict__ qlo,
                            const ushort* __restrict__ khi, const ushort* __restrict__ klo,
                            const ushort* __restrict__ vT, const ushort* __restrict__ tabBf,
                            const unsigned* __restrict__ idxP,
                            float* __restrict__ pO, float* __restrict__ pL) {
  __shared__ ushort tbf[10240];                        // 20 KB
  __shared__ __align__(16) ushort pbuf[8][16 * PBS];   // 9.2 KB
  __shared__ __align__(16) ushort stg[2][6144];        // 2 x 12 KB K/V stage
  int tid = threadIdx.x;
  int lane = tid & 63;
  int w = tid >> 6;

  int bid = blockIdx.x;                 // 0..1151
  int qb = bid >> 5;                    // 0..35 : 64-q-row tile
  int k8 = bid & 7;
  int j4 = (bid >> 3) & 3;
  int y  = k8 + 8 * j4;                 // 0..31 ; fixed y -> fixed bid%8 -> one XCD
  int s = y & 3, h = y >> 2;

  const ushort* tsrc = tabBf + h * TABP;
#pragma unroll
  for (int i = 0; i < 5; ++i) {
    int off = i * 2048 + tid * 8;
    *(int4*)&tbf[off] = *(const int4*)&tsrc[off];
  }

  int g = lane >> 4, c = lane & 15;
  int q0 = qb * 64 + w * 16;
  int qg0 = q0 >> 2;
  size_t rowA = (size_t)h * NSEQ;              // batch 0, head h
  size_t rowB = (size_t)(NHEADS + h) * NSEQ;   // batch 1, head h
  int m0 = s * MSP;

  // ---- staging geometry: thread covers 16B unit u=tid&127 of 3 subtile-pairs
  int su   = tid & 127;
  int srow = su & 31;          // tile row (K: m-row ; V: dim)
  int sslt = su >> 5;          // 16B slot
  const ushort* kb0 = (tid < 128) ? khi : klo;
  const ushort* sA = kb0 + (rowA + m0 + srow) * HDIM + sslt * 8;
  const ushort* sB = kb0 + (rowB + m0 + srow) * HDIM + sslt * 8;
  const ushort* sV = vT + ((size_t)(((tid < 128) ? h : NHEADS + h) * HDIM + srow)) * NSEQ
                     + m0 + sslt * 8;
  unsigned dwb = (unsigned)(tid & 192) * 8;    // wave-uniform dest base (elems)

#define STAGE(DP) do {                         \
    GL16(sA, (DP) + dwb);                      \
    GL16(sB, (DP) + 2048 + dwb);               \
    GL16(sV, (DP) + 4096 + dwb);               \
    sA += 32 * HDIM; sB += 32 * HDIM; sV += 32; \
  } while (0)

  short8 qAh = *(const short8*)&qhi[(rowA + q0 + c) * HDIM + g * 8];
  short8 qAl = *(const short8*)&qlo[(rowA + q0 + c) * HDIM + g * 8];
  short8 qBh = *(const short8*)&qhi[(rowB + q0 + c) * HDIM + g * 8];
  short8 qBl = *(const short8*)&qlo[(rowB + q0 + c) * HDIM + g * 8];

  unsigned oIb = (unsigned)(((unsigned)(qg0 + g) * NCHUNK + (m0 >> 5)) * 64 + c * 4);
  unsigned oI  = oIb;
  uint4v ia = __builtin_nontemporal_load((const uint4v*)&idxP[oI]);

  STAGE(&stg[0][0]);              // prologue stage of tile m0
  __syncthreads();                // drains tbf writes + prologue gload_lds

  short one = (c == 0) ? (short)0x3F80 : (short)0;
  short8 onesB = {one, one, one, one, one, one, one, one};

  f32x4 oa0 = {0,0,0,0}, oa1 = {0,0,0,0}, ob0 = {0,0,0,0}, ob1 = {0,0,0,0};
  f32x4 la = {0,0,0,0}, lb = {0,0,0,0};
  ushort* pba = pbuf[w * 2];
  ushort* pbb = pbuf[w * 2 + 1];

  int kbo = g * 256 + c * 8;      // frag base within a 2KB subtile (elems)
  int cur = 0;

  for (int mt = m0; mt < m0 + MSP; mt += 32) {
    bool lastit = (mt + 32 >= m0 + MSP);
    unsigned oIn = lastit ? oIb : oI + 64;
    uint4v ian = __builtin_nontemporal_load((const uint4v*)&idxP[oIn]);
    oI = oIn;
    if (!lastit) STAGE(&stg[cur ^ 1][0]);      // async prefetch of next tile

    const ushort* S = &stg[cur][0];
    short8 ak0h = *(const short8*)&S[kbo];
    short8 ak1h = *(const short8*)&S[kbo + 128];
    short8 ak0l = *(const short8*)&S[1024 + kbo];
    short8 ak1l = *(const short8*)&S[1024 + kbo + 128];
    short8 bk0h = *(const short8*)&S[2048 + kbo];
    short8 bk1h = *(const short8*)&S[2048 + kbo + 128];
    short8 bk0l = *(const short8*)&S[3072 + kbo];
    short8 bk1l = *(const short8*)&S[3072 + kbo + 128];

    f32x4 sa0 = {0,0,0,0}, sa1 = {0,0,0,0}, sb0 = {0,0,0,0}, sb1 = {0,0,0,0};
    sa0 = MFMA16(qAh, ak0h, sa0);
    sa1 = MFMA16(qAh, ak1h, sa1);
    sb0 = MFMA16(qBh, bk0h, sb0);
    sb1 = MFMA16(qBh, bk1h, sb1);
    sa0 = MFMA16(qAl, ak0h, sa0);
    sa1 = MFMA16(qAl, ak1h, sa1);
    sb0 = MFMA16(qBl, bk0h, sb0);
    sb1 = MFMA16(qBl, bk1h, sb1);
    sa0 = MFMA16(qAh, ak0l, sa0);
    sa1 = MFMA16(qAh, ak1l, sa1);
    sb0 = MFMA16(qBh, bk0l, sb0);
    sb1 = MFMA16(qBh, bk1l, sb1);

    // bias gathers (batch-shared) + exp2 + pack
    unsigned ip[4] = {ia.x, ia.y, ia.z, ia.w};
    float b0[4], b1[4];
#pragma unroll
    for (int r = 0; r < 4; ++r) {
      b0[r] = bf2f(tbf[ip[r] & 0xFFFF]);
      b1[r] = bf2f(tbf[ip[r] >> 16]);
    }
#pragma unroll
    for (int r = 0; r < 4; ++r) {
      float pA0 = fexp2(sa0[r] + b0[r]);
      float pA1 = fexp2(sa1[r] + b1[r]);
      *(unsigned*)&pba[(g * 4 + r) * PBS + 2 * c] = pack_trunc(pA0, pA1);
      float pB0 = fexp2(sb0[r] + b0[r]);
      float pB1 = fexp2(sb1[r] + b1[r]);
      *(unsigned*)&pbb[(g * 4 + r) * PBS + 2 * c] = pack_trunc(pB0, pB1);
    }

    short4v paA = *(const short4v*)&pba[c * PBS + g * 8];
    short4v paB = *(const short4v*)&pba[c * PBS + g * 8 + 4];
    short8 pfa = __builtin_shufflevector(paA, paB, 0, 1, 2, 3, 4, 5, 6, 7);
    short4v pbA = *(const short4v*)&pbb[c * PBS + g * 8];
    short4v pbB = *(const short4v*)&pbb[c * PBS + g * 8 + 4];
    short8 pfb = __builtin_shufflevector(pbA, pbB, 0, 1, 2, 3, 4, 5, 6, 7);

    short8 vf0 = *(const short8*)&S[4096 + kbo];
    short8 vf1 = *(const short8*)&S[4096 + kbo + 128];
    short8 wf0 = *(const short8*)&S[5120 + kbo];
    short8 wf1 = *(const short8*)&S[5120 + kbo + 128];

    oa0 = MFMA16(pfa, vf0, oa0);
    oa1 = MFMA16(pfa, vf1, oa1);
    ob0 = MFMA16(pfb, wf0, ob0);
    ob1 = MFMA16(pfb, wf1, ob1);
    la  = MFMA16(pfa, onesB, la);
    lb  = MFMA16(pfb, onesB, lb);

    ia = ian;
    __syncthreads();       // drains this iter's gload_lds; releases stg[cur]
    cur ^= 1;
  }
#undef STAGE

  size_t prowA = (size_t)s * RTOT + rowA;
  size_t prowB = (size_t)s * RTOT + rowB;
#pragma unroll
  for (int r = 0; r < 4; ++r) {
    size_t pra = prowA + q0 + g * 4 + r;
    __builtin_nontemporal_store(oa0[r], &pO[pra * HDIM + c]);
    __builtin_nontemporal_store(oa1[r], &pO[pra * HDIM + 16 + c]);
    size_t prb = prowB + q0 + g * 4 + r;
    __builtin_nontemporal_store(ob0[r], &pO[prb * HDIM + c]);
    __builtin_nontemporal_store(ob1[r], &pO[prb * HDIM + 16 + c]);
    if (c == 0) {
      __builtin_nontemporal_store(la[r], &pL[pra]);
      __builtin_nontemporal_store(lb[r], &pL[prb]);
    }
  }
}

// ------- fused merge + proj GEMM: 32-row tiles, 144 blocks -------
#define ALD 264
__launch_bounds__(256)
__global__ void gemm_proj_fused(const float* __restrict__ pO, const float* __restrict__ pL,
                                const float* __restrict__ Wp,
                                const float* __restrict__ bias, float* __restrict__ C) {
  __shared__ __align__(16) ushort Ahs[32 * ALD];
  __shared__ __align__(16) ushort Als[32 * ALD];
  int tid = threadIdx.x;
  int m0 = blockIdx.x * 32;
  int b = (m0 >= NSEQ) ? 1 : 0;
  int nb = m0 - b * NSEQ;

  {
    int rr = tid >> 3;          // 0..31 row
    int q  = tid & 3;           // 8-float chunk within head
    int hp = (tid >> 2) & 1;    // head half: heads hp*4 .. hp*4+3
    int n = nb + rr;
#pragma unroll
    for (int hh = 0; hh < 4; ++hh) {
      int h = hp * 4 + hh;
      size_t bhn = (size_t)(b * NHEADS + h) * NSEQ + n;
      float L = 0.f;
#pragma unroll
      for (int sp = 0; sp < SPLITS; ++sp) L += pL[(size_t)sp * RTOT + bhn];
      float inv = 1.f / L;
      float a[8] = {0.f, 0.f, 0.f, 0.f, 0.f, 0.f, 0.f, 0.f};
#pragma unroll
      for (int sp = 0; sp < SPLITS; ++sp) {
        const float* src = &pO[((size_t)sp * RTOT + bhn) * HDIM + q * 8];
        float4 v0 = *(const float4*)&src[0];
        float4 v1 = *(const float4*)&src[4];
        a[0] += v0.x; a[1] += v0.y; a[2] += v0.z; a[3] += v0.w;
        a[4] += v1.x; a[5] += v1.y; a[6] += v1.z; a[7] += v1.w;
      }
      ushort hi8[8], lo8[8];
#pragma unroll
      for (int i = 0; i < 8; ++i) {
        float v = a[i] * inv;
        ushort hh2 = f2bf(v);
        hi8[i] = hh2;
        lo8[i] = f2bf(v - bf2f(hh2));
      }
      int k = h * 32 + q * 8;
      *(int4*)&Ahs[rr * ALD + k] = *(int4*)hi8;
      *(int4*)&Als[rr * ALD + k] = *(int4*)lo8;
    }
  }
  __syncthreads();

  int lane = tid & 63, w = tid >> 6;
  int g = lane >> 4, c = lane & 15;
  int n0 = w * 64;
  f32x4 acc[2][4] = {};
  for (int k0 = 0; k0 < DIMC; k0 += 32) {
    short8 bfh[4], bfl[4];
#pragma unroll
    for (int nt = 0; nt < 4; ++nt)
      cvt8(&Wp[(size_t)(n0 + nt * 16 + c) * DIMC + k0 + g * 8], &bfh[nt], &bfl[nt]);
#pragma unroll
    for (int mt = 0; mt < 2; ++mt) {
      short8 ah = *(const short8*)&Ahs[(mt * 16 + c) * ALD + k0 + g * 8];
      short8 al = *(const short8*)&Als[(mt * 16 + c) * ALD + k0 + g * 8];
#pragma unroll
      for (int nt = 0; nt < 4; ++nt) {
        acc[mt][nt] = MFMA16(ah, bfh[nt], acc[mt][nt]);
        acc[mt][nt] = MFMA16(al, bfh[nt], acc[mt][nt]);
        acc[mt][nt] = MFMA16(ah, bfl[nt], acc[mt][nt]);
      }
    }
  }
#pragma unroll
  for (int nt = 0; nt < 4; ++nt) {
    float bv = bias[n0 + nt * 16 + c];
#pragma unroll
    for (int mt = 0; mt < 2; ++mt)
#pragma unroll
      for (int r = 0; r < 4; ++r)
        C[(size_t)(m0 + mt * 16 + g * 4 + r) * DIMC + n0 + nt * 16 + c] = acc[mt][nt][r] + bv;
  }
}

extern "C" void kernel_launch(void* const* d_in, const int* in_sizes, int n_in,
                              void* d_out, int out_size, void* d_ws, size_t ws_size,
                              hipStream_t stream) {
  const float* x    = (const float*)d_in[0];
  const int*   idx  = (const int*)d_in[1];
  const float* tbl  = (const float*)d_in[2];
  const float* sls  = (const float*)d_in[3];
  const float* Wqkv = (const float*)d_in[5];
  const float* bqkv = (const float*)d_in[6];
  const float* temp = (const float*)d_in[7];
  const float* qe   = (const float*)d_in[8];
  const float* Wp   = (const float*)d_in[9];
  const float* bp   = (const float*)d_in[10];
  const float* W1   = (const float*)d_in[11];
  const float* b1   = (const float*)d_in[12];
  const float* W2   = (const float*)d_in[13];
  const float* b2   = (const float*)d_in[14];

  float* ws   = (float*)d_ws;
  float* pO   = ws;                                       // 4*RTOT*HDIM = 4,718,592 f
  float* pL   = pO + (size_t)SPLITS * RTOT * HDIM;        // 147,456 f
  unsigned* idxP = (unsigned*)(pL + (size_t)SPLITS * RTOT);
  ushort* u   = (ushort*)(idxP + IDXP_ELEMS);
  ushort* qhi = u;                u += (size_t)RTOT * HDIM;
  ushort* qlo = u;                u += (size_t)RTOT * HDIM;
  ushort* khi = u;                u += (size_t)RTOT * HDIM;
  ushort* klo = u;                u += (size_t)RTOT * HDIM;
  ushort* vT  = u;                u += (size_t)RTOT * HDIM;
  ushort* tabBf = u;              u += 73728;
  float* out  = (float*)d_out;

  pack_kernel<<<dim3(IDXP4_BLOCKS), dim3(256), 0, stream>>>(idx, idxP);
  pre_kernel<<<dim3(CPB_BLOCKS + QKV_BLOCKS), dim3(256), 0, stream>>>(
      x, Wqkv, tbl, W1, b1, W2, b2, bqkv, temp, sls, qe,
      qhi, qlo, khi, klo, vT, tabBf);
  attn_kernel<<<dim3((NSEQ / 64) * NHEADS * SPLITS), dim3(256), 0, stream>>>(
      qhi, qlo, khi, klo, vT, tabBf, idxP, pO, pL);
  gemm_proj_fused<<<dim3((BB * NSEQ) / 32), dim3(256), 0, stream>>>(
      pO, pL, Wp, bp, out);
}

// Round 9
// 196.596 us; speedup vs baseline: 1.2471x; 1.0305x over previous
//
#include <hip/hip_runtime.h>
#include <math.h>

#define DIMC 256
#define NHEADS 8
#define HDIM 32
#define CPBH 512
#define BB 2
#define NSEQ 2304
#define TAB 9025
#define TABP 9040                  // padded table stride
#define RTOT (BB*NHEADS*NSEQ)      // 36864
#define SPLITS 4
#define MSP (NSEQ/SPLITS)          // 576 m per split
#define PBS 36                     // pbuf row stride in u16
#define NCHUNK (NSEQ/32)           // 72
#define LOG2E 1.44269504088896340736f

#define IDXP_ELEMS    (NSEQ * NCHUNK * 16)             // 2,654,208
#define IDXP4_BLOCKS  (IDXP_ELEMS / 1024)              // 2592
#define CPB_BLOCKS    ((TAB + 63) / 64)                // 142
#define QKV_BLOCKS    (12 * 72)                        // 864

typedef unsigned short ushort;
typedef __attribute__((ext_vector_type(8))) short short8;
typedef __attribute__((ext_vector_type(4))) short short4v;
typedef __attribute__((ext_vector_type(4))) float f32x4;

#define MFMA16(a,b,c) __builtin_amdgcn_mfma_f32_16x16x32_bf16((a),(b),(c),0,0,0)

// async global->LDS 16B copy; dest = wave-uniform base + lane*16
#define GL16(SRC, DST) __builtin_amdgcn_global_load_lds( \
    (const __attribute__((address_space(1))) void*)(SRC), \
    (__attribute__((address_space(3))) void*)(DST), 16, 0, 0)

__device__ __forceinline__ ushort f2bf(float x) {          // RNE fp32->bf16
  unsigned u = __float_as_uint(x);
  u += 0x7FFFu + ((u >> 16) & 1u);
  return (ushort)(u >> 16);
}
__device__ __forceinline__ float bf2f(ushort b) {
  return __uint_as_float(((unsigned)b) << 16);
}
__device__ __forceinline__ float fexp2(float x) {
#if defined(__has_builtin)
#if __has_builtin(__builtin_amdgcn_exp2f)
  return __builtin_amdgcn_exp2f(x);
#else
  return exp2f(x);
#endif
#else
  return exp2f(x);
#endif
}
__device__ __forceinline__ unsigned pack_trunc(float p0, float p1) {
  return __builtin_amdgcn_perm(__float_as_uint(p1), __float_as_uint(p0), 0x07060302u);
}
// load 8 consecutive fp32, emit split-bf16 hi/lo frags
__device__ __forceinline__ void cvt8(const float* __restrict__ p, short8* hi, short8* lo) {
  float4 v0 = *(const float4*)p;
  float4 v1 = *(const float4*)(p + 4);
  float vv[8] = {v0.x, v0.y, v0.z, v0.w, v1.x, v1.y, v1.z, v1.w};
  short8 h, l;
#pragma unroll
  for (int i = 0; i < 8; ++i) {
    ushort hh = f2bf(vv[i]);
    h[i] = (short)hh;
    l[i] = (short)f2bf(vv[i] - bf2f(hh));
  }
  *hi = h; *lo = l;
}

// ======= idx pair-pack kernel (no LDS, pure memory) =======
__launch_bounds__(256)
__global__ void pack_kernel(const int* __restrict__ idx, unsigned* __restrict__ idxP) {
  int t4 = blockIdx.x * 256 + threadIdx.x;   // 0..663551
  int grp = t4 >> 4;                 // 0..41471
  int ch = grp % NCHUNK;
  int n4 = grp / NCHUNK;
  int m = ch * 32 + (t4 & 15);
  unsigned o[4];
#pragma unroll
  for (int i = 0; i < 4; ++i) {
    unsigned lo = (unsigned)idx[(size_t)(n4 * 4 + i) * NSEQ + m];
    unsigned hi = (unsigned)idx[(size_t)(n4 * 4 + i) * NSEQ + m + 16];
    o[i] = lo | (hi << 16);
  }
  *(uint4*)&idxP[(size_t)t4 * 4] = *(const uint4*)o;
}

// ======= PRE: cpb (blocks first) | fused QKV GEMM with in-block B-tile
// split-bf16 LDS staging (wq cvt done ONCE per block, not 16x) =======
__launch_bounds__(256)
__global__ void pre_kernel(const float* __restrict__ x, const float* __restrict__ wq,
                           const float* __restrict__ tbl, const float* __restrict__ W1,
                           const float* __restrict__ b1, const float* __restrict__ W2,
                           const float* __restrict__ b2,
                           const float* __restrict__ bias, const float* __restrict__ temp,
                           const float* __restrict__ sls, const float* __restrict__ qe,
                           ushort* __restrict__ qhi, ushort* __restrict__ qlo,
                           ushort* __restrict__ khi, ushort* __restrict__ klo,
                           ushort* __restrict__ vT, ushort* __restrict__ tabBf) {
  __shared__ __align__(16) ushort smemu[33792];   // 66 KB union
  int blk = blockIdx.x;
  int tid = threadIdx.x;

  if (blk < CPB_BLOCKS) {
    // ---- CPB MLP, LDS-tiled ----
    float* smem = (float*)smemu;
    float* w1b = smem;                  // 2048 f
    float* w2t = smem + 2048;           // 4096 f
    float* part = smem + 6144;          // 2048 f
    for (int i = tid; i < CPBH; i += 256) {
      w1b[i * 4 + 0] = W1[2 * i];
      w1b[i * 4 + 1] = W1[2 * i + 1];
      w1b[i * 4 + 2] = b1[i];
      w1b[i * 4 + 3] = 0.f;
    }
    for (int i = tid; i < CPBH * NHEADS; i += 256)
      w2t[(i & (CPBH - 1)) * NHEADS + (i >> 9)] = W2[i];
    int tl = tid & 63, jc = tid >> 6;
    int t = blk * 64 + tl;
    bool valid = t < TAB;
    float c0 = 0.f, c1 = 0.f;
    if (valid) { c0 = tbl[2 * t]; c1 = tbl[2 * t + 1]; }
    __syncthreads();
    float acc[NHEADS];
#pragma unroll
    for (int h = 0; h < NHEADS; ++h) acc[h] = 0.f;
    for (int j = jc * 128; j < jc * 128 + 128; ++j) {
      float4 wv = *(const float4*)&w1b[j * 4];
      float hid = fmaxf(fmaf(c0, wv.x, fmaf(c1, wv.y, wv.z)), 0.f);
      float4 wa = *(const float4*)&w2t[j * NHEADS];
      float4 wb = *(const float4*)&w2t[j * NHEADS + 4];
      acc[0] = fmaf(hid, wa.x, acc[0]);
      acc[1] = fmaf(hid, wa.y, acc[1]);
      acc[2] = fmaf(hid, wa.z, acc[2]);
      acc[3] = fmaf(hid, wa.w, acc[3]);
      acc[4] = fmaf(hid, wb.x, acc[4]);
      acc[5] = fmaf(hid, wb.y, acc[5]);
      acc[6] = fmaf(hid, wb.z, acc[6]);
      acc[7] = fmaf(hid, wb.w, acc[7]);
    }
#pragma unroll
    for (int h = 0; h < NHEADS; ++h) part[((size_t)jc * 64 + tl) * NHEADS + h] = acc[h];
    __syncthreads();
    if (jc == 0 && valid) {
#pragma unroll
      for (int h = 0; h < NHEADS; ++h) {
        float s = b2[h];
#pragma unroll
        for (int p = 0; p < 4; ++p) s += part[((size_t)p * 64 + tl) * NHEADS + h];
        tabBf[h * TABP + t] = f2bf(s * LOG2E);
      }
    }
  } else {
    // ---- fused QKV GEMM: B-tile (64 rows of wq) split-bf16 staged in LDS ----
    ushort* bsh = smemu;                 // [64][264] hi
    ushort* bsl = smemu + 64 * 264;      // [64][264] lo
    float (*vbuf)[65] = (float(*)[65])smemu;   // union, used after k-loop
    int t = blk - CPB_BLOCKS;
    int n0 = (t % 12) * 64, m0 = (t / 12) * 64;
    int lane = tid & 63, w = tid >> 6;
    int g = lane >> 4, c = lane & 15;
    int mw = m0 + w * 16;
    const int K = DIMC;

    {   // stage: each thread converts 64 elems (8 cvt8), once per block
      int rr = tid >> 2, cq = (tid & 3) * 64;
#pragma unroll
      for (int j = 0; j < 64; j += 8) {
        short8 hh, ll;
        cvt8(&wq[(size_t)(n0 + rr) * K + cq + j], &hh, &ll);
        *(short8*)&bsh[rr * 264 + cq + j] = hh;
        *(short8*)&bsl[rr * 264 + cq + j] = ll;
      }
    }
    __syncthreads();

    f32x4 acc[4] = {{0,0,0,0},{0,0,0,0},{0,0,0,0},{0,0,0,0}};
#pragma unroll 2
    for (int k0 = 0; k0 < K; k0 += 32) {
      short8 ah, al;
      cvt8(&x[(size_t)(mw + c) * K + k0 + g * 8], &ah, &al);
#pragma unroll
      for (int nt = 0; nt < 4; ++nt) {
        int br = (nt * 16 + c) * 264 + k0 + g * 8;
        short8 bh = *(const short8*)&bsh[br];
        short8 bl = *(const short8*)&bsl[br];
        acc[nt] = MFMA16(ah, bh, acc[nt]);
        acc[nt] = MFMA16(al, bh, acc[nt]);
        acc[nt] = MFMA16(ah, bl, acc[nt]);
      }
    }
#pragma unroll
    for (int nt = 0; nt < 4; ++nt) {
      float bv = bias[n0 + nt * 16 + c];
#pragma unroll
      for (int r = 0; r < 4; ++r) acc[nt][r] += bv;
    }
    __syncthreads();   // all waves done reading bsh/bsl before vbuf overwrites

    int b = (m0 >= NSEQ) ? 1 : 0;
    int nb = m0 - b * NSEQ;
    int sect = n0 >> 8;
    int hloc = (n0 & 255) >> 5;

    if (sect < 2) {
#pragma unroll
      for (int H = 0; H < 2; ++H) {
        int head = hloc + H;
        float scale = (sect == 0) ? log1pf(expf(temp[head])) * sls[0] * LOG2E : 0.f;
#pragma unroll
        for (int r = 0; r < 4; ++r) {
          float ss = acc[2*H][r]*acc[2*H][r] + acc[2*H+1][r]*acc[2*H+1][r];
          ss += __shfl_xor(ss, 1);
          ss += __shfl_xor(ss, 2);
          ss += __shfl_xor(ss, 4);
          ss += __shfl_xor(ss, 8);
          float inv = 1.f / fmaxf(sqrtf(ss), 1e-12f);
#pragma unroll
          for (int half = 0; half < 2; ++half) {
            int d = half * 16 + c;
            float val = acc[2*H + half][r] * inv;
            if (sect == 0) val = (val + qe[head * HDIM + d]) * scale;
            vbuf[w * 16 + g * 4 + r][H * 32 + d] = val;
          }
        }
      }
      __syncthreads();
      int plane = tid >> 7;
      int seg = tid & 127;
      int head = seg >> 6, row = seg & 63;
      const float* srcrow = &vbuf[row][head * 32];
      ushort out16[32];
#pragma unroll
      for (int i = 0; i < 32; ++i) {
        float v = srcrow[i];
        ushort hh = f2bf(v);
        out16[i] = plane ? f2bf(v - bf2f(hh)) : hh;
      }
      ushort* dstp = plane ? (sect == 0 ? qlo : klo) : (sect == 0 ? qhi : khi);
      size_t off = ((size_t)(b * NHEADS + hloc + head) * NSEQ + nb + row) * HDIM;
#pragma unroll
      for (int q4 = 0; q4 < 4; ++q4)
        *(int4*)&dstp[off + q4 * 8] = ((int4*)out16)[q4];
    } else {
#pragma unroll
      for (int nt = 0; nt < 4; ++nt)
#pragma unroll
        for (int r = 0; r < 4; ++r)
          vbuf[w * 16 + g * 4 + r][nt * 16 + c] = acc[nt][r];
      __syncthreads();
      int hbase = (n0 - 512) >> 5;
#pragma unroll
      for (int it = 0; it < 16; ++it) {
        int dloc = (tid >> 6) * 16 + it;
        int p = tid & 63;
        int pp = p & 31;
        int nsrc = (p & 32) + (pp & 1) * 16 + (pp >> 1);
        float v = vbuf[nsrc][dloc];
        int head = hbase + (dloc >> 5), d = dloc & 31;
        vT[((size_t)((b * NHEADS + head) * HDIM + d)) * NSEQ + nb + p] = f2bf(v);
      }
    }
  }
}

// ------- MFMA flash attention: r5 2-phase async-LDS dbuf + 32 q-rows/wave.
// LDS-read-bound diagnosis (r5-r8): 12 ds_read_b128 of K/V per wave-iter fed
// only 18 MFMA. Doubling q-rows per wave (2 Q-frags/batch) feeds 36 MFMA from
// the SAME 12 reads -> LDS reads per score halve. Grid halves to 576 blocks
// (18 qb x 32 (h,s)); NT=18 unchanged; occupancy still LDS-capped 2 blocks/CU
// so extra VGPR (~160) is free. NT hints reverted (r8: WRITE +1.7MB, -5.5us).
__launch_bounds__(256)
__global__ void attn_kernel(const ushort* __restrict__ qhi, const ushort* __restrict__ qlo,
                            const ushort* __restrict__ khi, const ushort* __restrict__ klo,
                            const ushort* __restrict__ vT, const ushort* __restrict__ tabBf,
                            const unsigned* __restrict__ idxP,
                            float* __restrict__ pO, float* __restrict__ pL) {
  __shared__ ushort tbf[10240];                        // 20 KB
  __shared__ __align__(16) ushort pbuf[16][16 * PBS];  // 18 KB (16 P-tiles)
  __shared__ __align__(16) ushort stg[2][6144];        // 2 x 12 KB K/V stage
  int tid = threadIdx.x;
  int lane = tid & 63;
  int w = tid >> 6;

  int bid = blockIdx.x;                 // 0..575
  int qb = bid >> 5;                    // 0..17 : 128-q-row tile
  int k8 = bid & 7;
  int j4 = (bid >> 3) & 3;
  int y  = k8 + 8 * j4;                 // 0..31 ; fixed y -> fixed bid%8 -> one XCD
  int s = y & 3, h = y >> 2;

  const ushort* tsrc = tabBf + h * TABP;
#pragma unroll
  for (int i = 0; i < 5; ++i) {
    int off = i * 2048 + tid * 8;
    *(int4*)&tbf[off] = *(const int4*)&tsrc[off];
  }

  int g = lane >> 4, c = lane & 15;
  int q0 = qb * 128 + w * 32;           // this wave: q-rows [q0,q0+32)
  int qg0 = q0 >> 2;
  size_t rowA = (size_t)h * NSEQ;              // batch 0, head h
  size_t rowB = (size_t)(NHEADS + h) * NSEQ;   // batch 1, head h
  int m0 = s * MSP;

  // ---- staging geometry: thread covers 16B unit u=tid&127 of 3 subtile-pairs
  int su   = tid & 127;
  int srow = su & 31;          // tile row (K: m-row ; V: dim)
  int sslt = su >> 5;          // 16B slot
  const ushort* kb0 = (tid < 128) ? khi : klo;
  const ushort* sA = kb0 + (rowA + m0 + srow) * HDIM + sslt * 8;
  const ushort* sB = kb0 + (rowB + m0 + srow) * HDIM + sslt * 8;
  const ushort* sV = vT + ((size_t)(((tid < 128) ? h : NHEADS + h) * HDIM + srow)) * NSEQ
                     + m0 + sslt * 8;
  unsigned dwb = (unsigned)(tid & 192) * 8;    // wave-uniform dest base (elems)

#define STAGE(DP) do {                         \
    GL16(sA, (DP) + dwb);                      \
    GL16(sB, (DP) + 2048 + dwb);               \
    GL16(sV, (DP) + 4096 + dwb);               \
    sA += 32 * HDIM; sB += 32 * HDIM; sV += 32; \
  } while (0)

  short8 qA0h = *(const short8*)&qhi[(rowA + q0 + c) * HDIM + g * 8];
  short8 qA0l = *(const short8*)&qlo[(rowA + q0 + c) * HDIM + g * 8];
  short8 qA1h = *(const short8*)&qhi[(rowA + q0 + 16 + c) * HDIM + g * 8];
  short8 qA1l = *(const short8*)&qlo[(rowA + q0 + 16 + c) * HDIM + g * 8];
  short8 qB0h = *(const short8*)&qhi[(rowB + q0 + c) * HDIM + g * 8];
  short8 qB0l = *(const short8*)&qlo[(rowB + q0 + c) * HDIM + g * 8];
  short8 qB1h = *(const short8*)&qhi[(rowB + q0 + 16 + c) * HDIM + g * 8];
  short8 qB1l = *(const short8*)&qlo[(rowB + q0 + 16 + c) * HDIM + g * 8];

  const unsigned IOFF1 = 4u * NCHUNK * 64;     // frag1 is 4 q-groups later
  unsigned oIb = (unsigned)(((unsigned)(qg0 + g) * NCHUNK + (m0 >> 5)) * 64 + c * 4);
  unsigned oI  = oIb;
  uint4 ia = *(const uint4*)&idxP[oI];
  uint4 ja = *(const uint4*)&idxP[oI + IOFF1];

  STAGE(&stg[0][0]);              // prologue stage of tile m0
  __syncthreads();                // drains tbf writes + prologue gload_lds

  short one = (c == 0) ? (short)0x3F80 : (short)0;
  short8 onesB = {one, one, one, one, one, one, one, one};

  f32x4 oa00 = {0,0,0,0}, oa01 = {0,0,0,0}, oa10 = {0,0,0,0}, oa11 = {0,0,0,0};
  f32x4 ob00 = {0,0,0,0}, ob01 = {0,0,0,0}, ob10 = {0,0,0,0}, ob11 = {0,0,0,0};
  f32x4 la0 = {0,0,0,0}, la1 = {0,0,0,0}, lb0 = {0,0,0,0}, lb1 = {0,0,0,0};
  ushort* pba0 = pbuf[w * 4];
  ushort* pba1 = pbuf[w * 4 + 1];
  ushort* pbb0 = pbuf[w * 4 + 2];
  ushort* pbb1 = pbuf[w * 4 + 3];

  int kbo = g * 256 + c * 8;      // frag base within a 2KB subtile (elems)
  int cur = 0;

  for (int mt = m0; mt < m0 + MSP; mt += 32) {
    bool lastit = (mt + 32 >= m0 + MSP);
    unsigned oIn = lastit ? oIb : oI + 64;
    uint4 ian = *(const uint4*)&idxP[oIn];
    uint4 jan = *(const uint4*)&idxP[oIn + IOFF1];
    oI = oIn;
    if (!lastit) STAGE(&stg[cur ^ 1][0]);      // async prefetch of next tile

    const ushort* S = &stg[cur][0];
    short8 ak0h = *(const short8*)&S[kbo];
    short8 ak1h = *(const short8*)&S[kbo + 128];
    short8 ak0l = *(const short8*)&S[1024 + kbo];
    short8 ak1l = *(const short8*)&S[1024 + kbo + 128];
    short8 bk0h = *(const short8*)&S[2048 + kbo];
    short8 bk1h = *(const short8*)&S[2048 + kbo + 128];
    short8 bk0l = *(const short8*)&S[3072 + kbo];
    short8 bk1l = *(const short8*)&S[3072 + kbo + 128];

    // QK^T: 24 MFMA fed by the 8 K-frag reads above
    f32x4 sa0 = {0,0,0,0}, sa1 = {0,0,0,0}, ta0 = {0,0,0,0}, ta1 = {0,0,0,0};
    f32x4 sb0 = {0,0,0,0}, sb1 = {0,0,0,0}, tb0 = {0,0,0,0}, tb1 = {0,0,0,0};
    sa0 = MFMA16(qA0h, ak0h, sa0);
    sa1 = MFMA16(qA0h, ak1h, sa1);
    ta0 = MFMA16(qA1h, ak0h, ta0);
    ta1 = MFMA16(qA1h, ak1h, ta1);
    sb0 = MFMA16(qB0h, bk0h, sb0);
    sb1 = MFMA16(qB0h, bk1h, sb1);
    tb0 = MFMA16(qB1h, bk0h, tb0);
    tb1 = MFMA16(qB1h, bk1h, tb1);
    sa0 = MFMA16(qA0l, ak0h, sa0);
    sa1 = MFMA16(qA0l, ak1h, sa1);
    ta0 = MFMA16(qA1l, ak0h, ta0);
    ta1 = MFMA16(qA1l, ak1h, ta1);
    sb0 = MFMA16(qB0l, bk0h, sb0);
    sb1 = MFMA16(qB0l, bk1h, sb1);
    tb0 = MFMA16(qB1l, bk0h, tb0);
    tb1 = MFMA16(qB1l, bk1h, tb1);
    sa0 = MFMA16(qA0h, ak0l, sa0);
    sa1 = MFMA16(qA0h, ak1l, sa1);
    ta0 = MFMA16(qA1h, ak0l, ta0);
    ta1 = MFMA16(qA1h, ak1l, ta1);
    sb0 = MFMA16(qB0h, bk0l, sb0);
    sb1 = MFMA16(qB0h, bk1l, sb1);
    tb0 = MFMA16(qB1h, bk0l, tb0);
    tb1 = MFMA16(qB1h, bk1l, tb1);

    // bias gathers (batch-shared; ia for frag0 rows, ja for frag1 rows)
    unsigned ip[4] = {ia.x, ia.y, ia.z, ia.w};
    unsigned jp[4] = {ja.x, ja.y, ja.z, ja.w};
#pragma unroll
    for (int r = 0; r < 4; ++r) {
      float b0 = bf2f(tbf[ip[r] & 0xFFFF]);
      float b1 = bf2f(tbf[ip[r] >> 16]);
      *(unsigned*)&pba0[(g * 4 + r) * PBS + 2 * c] =
          pack_trunc(fexp2(sa0[r] + b0), fexp2(sa1[r] + b1));
      *(unsigned*)&pbb0[(g * 4 + r) * PBS + 2 * c] =
          pack_trunc(fexp2(sb0[r] + b0), fexp2(sb1[r] + b1));
      float d0 = bf2f(tbf[jp[r] & 0xFFFF]);
      float d1 = bf2f(tbf[jp[r] >> 16]);
      *(unsigned*)&pba1[(g * 4 + r) * PBS + 2 * c] =
          pack_trunc(fexp2(ta0[r] + d0), fexp2(ta1[r] + d1));
      *(unsigned*)&pbb1[(g * 4 + r) * PBS + 2 * c] =
          pack_trunc(fexp2(tb0[r] + d0), fexp2(tb1[r] + d1));
    }

#define LOADP(PB, DST) do {                                             \
    short4v pA_ = *(const short4v*)&(PB)[c * PBS + g * 8];              \
    short4v pB_ = *(const short4v*)&(PB)[c * PBS + g * 8 + 4];          \
    DST = __builtin_shufflevector(pA_, pB_, 0, 1, 2, 3, 4, 5, 6, 7);    \
  } while (0)
    short8 pfa0, pfa1, pfb0, pfb1;
    LOADP(pba0, pfa0);
    LOADP(pba1, pfa1);
    LOADP(pbb0, pfb0);
    LOADP(pbb1, pfb1);
#undef LOADP

    short8 vf0 = *(const short8*)&S[4096 + kbo];
    short8 vf1 = *(const short8*)&S[4096 + kbo + 128];
    short8 wf0 = *(const short8*)&S[5120 + kbo];
    short8 wf1 = *(const short8*)&S[5120 + kbo + 128];

    oa00 = MFMA16(pfa0, vf0, oa00);
    oa01 = MFMA16(pfa0, vf1, oa01);
    oa10 = MFMA16(pfa1, vf0, oa10);
    oa11 = MFMA16(pfa1, vf1, oa11);
    ob00 = MFMA16(pfb0, wf0, ob00);
    ob01 = MFMA16(pfb0, wf1, ob01);
    ob10 = MFMA16(pfb1, wf0, ob10);
    ob11 = MFMA16(pfb1, wf1, ob11);
    la0  = MFMA16(pfa0, onesB, la0);
    la1  = MFMA16(pfa1, onesB, la1);
    lb0  = MFMA16(pfb0, onesB, lb0);
    lb1  = MFMA16(pfb1, onesB, lb1);

    ia = ian; ja = jan;
    __syncthreads();       // drains this iter's gload_lds; releases stg[cur]
    cur ^= 1;
  }
#undef STAGE

  size_t prowA = (size_t)s * RTOT + rowA;
  size_t prowB = (size_t)s * RTOT + rowB;
#pragma unroll
  for (int r = 0; r < 4; ++r) {
    size_t pa0 = prowA + q0 + g * 4 + r;
    pO[pa0 * HDIM + c]      = oa00[r];
    pO[pa0 * HDIM + 16 + c] = oa01[r];
    size_t pa1 = pa0 + 16;
    pO[pa1 * HDIM + c]      = oa10[r];
    pO[pa1 * HDIM + 16 + c] = oa11[r];
    size_t pb0 = prowB + q0 + g * 4 + r;
    pO[pb0 * HDIM + c]      = ob00[r];
    pO[pb0 * HDIM + 16 + c] = ob01[r];
    size_t pb1 = pb0 + 16;
    pO[pb1 * HDIM + c]      = ob10[r];
    pO[pb1 * HDIM + 16 + c] = ob11[r];
    if (c == 0) {
      pL[pa0] = la0[r]; pL[pa1] = la1[r];
      pL[pb0] = lb0[r]; pL[pb1] = lb1[r];
    }
  }
}

// ------- fused merge + proj GEMM: 32-row tiles, 144 blocks -------
#define ALD 264
__launch_bounds__(256)
__global__ void gemm_proj_fused(const float* __restrict__ pO, const float* __restrict__ pL,
                                const float* __restrict__ Wp,
                                const float* __restrict__ bias, float* __restrict__ C) {
  __shared__ __align__(16) ushort Ahs[32 * ALD];
  __shared__ __align__(16) ushort Als[32 * ALD];
  int tid = threadIdx.x;
  int m0 = blockIdx.x * 32;
  int b = (m0 >= NSEQ) ? 1 : 0;
  int nb = m0 - b * NSEQ;

  {
    int rr = tid >> 3;          // 0..31 row
    int q  = tid & 3;           // 8-float chunk within head
    int hp = (tid >> 2) & 1;    // head half: heads hp*4 .. hp*4+3
    int n = nb + rr;
#pragma unroll
    for (int hh = 0; hh < 4; ++hh) {
      int h = hp * 4 + hh;
      size_t bhn = (size_t)(b * NHEADS + h) * NSEQ + n;
      float L = 0.f;
#pragma unroll
      for (int sp = 0; sp < SPLITS; ++sp) L += pL[(size_t)sp * RTOT + bhn];
      float inv = 1.f / L;
      float a[8] = {0.f, 0.f, 0.f, 0.f, 0.f, 0.f, 0.f, 0.f};
#pragma unroll
      for (int sp = 0; sp < SPLITS; ++sp) {
        const float* src = &pO[((size_t)sp * RTOT + bhn) * HDIM + q * 8];
        float4 v0 = *(const float4*)&src[0];
        float4 v1 = *(const float4*)&src[4];
        a[0] += v0.x; a[1] += v0.y; a[2] += v0.z; a[3] += v0.w;
        a[4] += v1.x; a[5] += v1.y; a[6] += v1.z; a[7] += v1.w;
      }
      ushort hi8[8], lo8[8];
#pragma unroll
      for (int i = 0; i < 8; ++i) {
        float v = a[i] * inv;
        ushort hh2 = f2bf(v);
        hi8[i] = hh2;
        lo8[i] = f2bf(v - bf2f(hh2));
      }
      int k = h * 32 + q * 8;
      *(int4*)&Ahs[rr * ALD + k] = *(int4*)hi8;
      *(int4*)&Als[rr * ALD + k] = *(int4*)lo8;
    }
  }
  __syncthreads();

  int lane = tid & 63, w = tid >> 6;
  int g = lane >> 4, c = lane & 15;
  int n0 = w * 64;
  f32x4 acc[2][4] = {};
  for (int k0 = 0; k0 < DIMC; k0 += 32) {
    short8 bfh[4], bfl[4];
#pragma unroll
    for (int nt = 0; nt < 4; ++nt)
      cvt8(&Wp[(size_t)(n0 + nt * 16 + c) * DIMC + k0 + g * 8], &bfh[nt], &bfl[nt]);
#pragma unroll
    for (int mt = 0; mt < 2; ++mt) {
      short8 ah = *(const short8*)&Ahs[(mt * 16 + c) * ALD + k0 + g * 8];
      short8 al = *(const short8*)&Als[(mt * 16 + c) * ALD + k0 + g * 8];
#pragma unroll
      for (int nt = 0; nt < 4; ++nt) {
        acc[mt][nt] = MFMA16(ah, bfh[nt], acc[mt][nt]);
        acc[mt][nt] = MFMA16(al, bfh[nt], acc[mt][nt]);
        acc[mt][nt] = MFMA16(ah, bfl[nt], acc[mt][nt]);
      }
    }
  }
#pragma unroll
  for (int nt = 0; nt < 4; ++nt) {
    float bv = bias[n0 + nt * 16 + c];
#pragma unroll
    for (int mt = 0; mt < 2; ++mt)
#pragma unroll
      for (int r = 0; r < 4; ++r)
        C[(size_t)(m0 + mt * 16 + g * 4 + r) * DIMC + n0 + nt * 16 + c] = acc[mt][nt][r] + bv;
  }
}

extern "C" void kernel_launch(void* const* d_in, const int* in_sizes, int n_in,
                              void* d_out, int out_size, void* d_ws, size_t ws_size,
                              hipStream_t stream) {
  const float* x    = (const float*)d_in[0];
  const int*   idx  = (const int*)d_in[1];
  const float* tbl  = (const float*)d_in[2];
  const float* sls  = (const float*)d_in[3];
  const float* Wqkv = (const float*)d_in[5];
  const float* bqkv = (const float*)d_in[6];
  const float* temp = (const float*)d_in[7];
  const float* qe   = (const float*)d_in[8];
  const float* Wp   = (const float*)d_in[9];
  const float* bp   = (const float*)d_in[10];
  const float* W1   = (const float*)d_in[11];
  const float* b1   = (const float*)d_in[12];
  const float* W2   = (const float*)d_in[13];
  const float* b2   = (const float*)d_in[14];

  float* ws   = (float*)d_ws;
  float* pO   = ws;                                       // 4*RTOT*HDIM = 4,718,592 f
  float* pL   = pO + (size_t)SPLITS * RTOT * HDIM;        // 147,456 f
  unsigned* idxP = (unsigned*)(pL + (size_t)SPLITS * RTOT);
  ushort* u   = (ushort*)(idxP + IDXP_ELEMS);
  ushort* qhi = u;                u += (size_t)RTOT * HDIM;
  ushort* qlo = u;                u += (size_t)RTOT * HDIM;
  ushort* khi = u;                u += (size_t)RTOT * HDIM;
  ushort* klo = u;                u += (size_t)RTOT * HDIM;
  ushort* vT  = u;                u += (size_t)RTOT * HDIM;
  ushort* tabBf = u;              u += 73728;
  float* out  = (float*)d_out;

  pack_kernel<<<dim3(IDXP4_BLOCKS), dim3(256), 0, stream>>>(idx, idxP);
  pre_kernel<<<dim3(CPB_BLOCKS + QKV_BLOCKS), dim3(256), 0, stream>>>(
      x, Wqkv, tbl, W1, b1, W2, b2, bqkv, temp, sls, qe,
      qhi, qlo, khi, klo, vT, tabBf);
  attn_kernel<<<dim3((NSEQ / 128) * NHEADS * SPLITS), dim3(256), 0, stream>>>(
      qhi, qlo, khi, klo, vT, tabBf, idxP, pO, pL);
  gemm_proj_fused<<<dim3((BB * NSEQ) / 32), dim3(256), 0, stream>>>(
      pO, pL, Wp, bp, out);
}